// Round 1
// baseline (92.728 us; speedup 1.0000x reference)
//
#include <hip/hip_runtime.h>

#define HH 512
#define WW 512
#define NB 32
#define NPIX (NB * HH * WW)

__device__ __forceinline__ float4 ldx4(const float* __restrict__ x, int b, int h, int w) {
    return *reinterpret_cast<const float4*>(x + ((((size_t)b * HH + h) * WW + w) << 2));
}

// full conv, KxK, 4->4 channels, weights HWIO [K][K][4][4]
template <int K>
__device__ __forceinline__ void conv_full(const float* __restrict__ x,
                                          const float* __restrict__ wgt,
                                          int b, int h, int w, float acc[4]) {
    constexpr int P = K / 2;
#pragma unroll
    for (int ki = 0; ki < K; ++ki) {
        int hh = h + ki - P;
        if (hh < 0 || hh >= HH) continue;
#pragma unroll
        for (int kj = 0; kj < K; ++kj) {
            int ww2 = w + kj - P;
            if (ww2 < 0 || ww2 >= WW) continue;
            float4 px = ldx4(x, b, hh, ww2);
            const float* wp = wgt + (ki * K + kj) * 16;  // [i][o] 4x4
            acc[0] += px.x * wp[0] + px.y * wp[4] + px.z * wp[8]  + px.w * wp[12];
            acc[1] += px.x * wp[1] + px.y * wp[5] + px.z * wp[9]  + px.w * wp[13];
            acc[2] += px.x * wp[2] + px.y * wp[6] + px.z * wp[10] + px.w * wp[14];
            acc[3] += px.x * wp[3] + px.y * wp[7] + px.z * wp[11] + px.w * wp[15];
        }
    }
}

// depthwise conv, KxK, weights HWIO [K][K][1][4]
template <int K>
__device__ __forceinline__ void conv_dw(const float* __restrict__ x,
                                        const float* __restrict__ wgt,
                                        int b, int h, int w, float acc[4]) {
    constexpr int P = K / 2;
#pragma unroll
    for (int ki = 0; ki < K; ++ki) {
        int hh = h + ki - P;
        if (hh < 0 || hh >= HH) continue;
#pragma unroll
        for (int kj = 0; kj < K; ++kj) {
            int ww2 = w + kj - P;
            if (ww2 < 0 || ww2 >= WW) continue;
            float4 px = ldx4(x, b, hh, ww2);
            const float* wp = wgt + (ki * K + kj) * 4;  // [c]
            acc[0] += px.x * wp[0];
            acc[1] += px.y * wp[1];
            acc[2] += px.z * wp[2];
            acc[3] += px.w * wp[3];
        }
    }
}

__global__ __launch_bounds__(256) void mixop_kernel(
    const float* __restrict__ x,
    const float* __restrict__ logits, const float* __restrict__ g,
    const float* __restrict__ w0, const float* __restrict__ w1,
    const float* __restrict__ w2, const float* __restrict__ w3,
    const float* __restrict__ w4,
    const float* __restrict__ gamma, const float* __restrict__ beta,
    const float* __restrict__ mean, const float* __restrict__ var,
    float* __restrict__ out) {
    size_t tid = (size_t)blockIdx.x * blockDim.x + threadIdx.x;
    if (tid >= (size_t)NPIX) return;

    // wave-uniform routing decision: argmax(logits + g), first-max wins
    int idx = 0;
    float best = logits[0] + g[0];
#pragma unroll
    for (int i = 1; i < 5; ++i) {
        float v = logits[i] + g[i];
        if (v > best) { best = v; idx = i; }
    }

    int w = (int)(tid & (WW - 1));
    int h = (int)((tid >> 9) & (HH - 1));
    int b = (int)(tid >> 18);

    float acc[4] = {0.f, 0.f, 0.f, 0.f};
    switch (idx) {
        case 0: {
            float4 px = ldx4(x, b, h, w);
            acc[0] = px.x * w0[0] + px.y * w0[4] + px.z * w0[8]  + px.w * w0[12];
            acc[1] = px.x * w0[1] + px.y * w0[5] + px.z * w0[9]  + px.w * w0[13];
            acc[2] = px.x * w0[2] + px.y * w0[6] + px.z * w0[10] + px.w * w0[14];
            acc[3] = px.x * w0[3] + px.y * w0[7] + px.z * w0[11] + px.w * w0[15];
            break;
        }
        case 1: conv_full<3>(x, w1, b, h, w, acc); break;
        case 2: conv_dw<3>(x, w2, b, h, w, acc); break;
        case 3: conv_full<5>(x, w3, b, h, w, acc); break;
        case 4: conv_dw<5>(x, w4, b, h, w, acc); break;
    }

    // inference BN + ReLU (branch idx's row)
    const float* ga = gamma + idx * 4;
    const float* be = beta + idx * 4;
    const float* mu = mean + idx * 4;
    const float* vr = var + idx * 4;
    float o[4];
#pragma unroll
    for (int c = 0; c < 4; ++c) {
        float iv = ga[c] * rsqrtf(vr[c] + 1e-5f);
        float v = acc[c] * iv + (be[c] - mu[c] * iv);
        o[c] = v > 0.f ? v : 0.f;
    }
    // scale = take(hard, index) == 1.0 exactly (onehot + soft - soft)
    *reinterpret_cast<float4*>(out + (tid << 2)) = make_float4(o[0], o[1], o[2], o[3]);
}

extern "C" void kernel_launch(void* const* d_in, const int* in_sizes, int n_in,
                              void* d_out, int out_size, void* d_ws, size_t ws_size,
                              hipStream_t stream) {
    const float* x      = (const float*)d_in[0];
    const float* logits = (const float*)d_in[1];
    const float* g      = (const float*)d_in[2];
    const float* w0     = (const float*)d_in[3];
    const float* w1     = (const float*)d_in[4];
    const float* w2     = (const float*)d_in[5];
    const float* w3     = (const float*)d_in[6];
    const float* w4     = (const float*)d_in[7];
    const float* gamma  = (const float*)d_in[8];
    const float* beta   = (const float*)d_in[9];
    const float* mean   = (const float*)d_in[10];
    const float* var    = (const float*)d_in[11];
    float* out = (float*)d_out;

    const int threads = 256;
    const int blocks = (NPIX + threads - 1) / threads;
    mixop_kernel<<<blocks, threads, 0, stream>>>(
        x, logits, g, w0, w1, w2, w3, w4, gamma, beta, mean, var, out);
}

// Round 2
// 84.452 us; speedup vs baseline: 1.0980x; 1.0980x over previous
//
#include <hip/hip_runtime.h>

typedef float f2 __attribute__((ext_vector_type(2)));

#define HH 512
#define WW 512
#define NB 32
#define VEC 4
#define GW_N (WW / VEC)              // 128 pixel-groups per row
#define NTHREAD (NB * HH * GW_N)     // 2,097,152
#define EPS 1e-5f

__device__ __forceinline__ float4 ldx4(const float* __restrict__ x, int b, int h, int w) {
    return *reinterpret_cast<const float4*>(x + ((((size_t)b * HH + h) * WW + w) << 2));
}

template <int K>
__device__ __forceinline__ void load_row(const float* __restrict__ x, int b, int hh,
                                         int wpix0, bool wsafe, float4 rb[VEC + K - 1]) {
    constexpr int P = K / 2;
    if (wsafe) {
#pragma unroll
        for (int j = 0; j < VEC + K - 1; ++j) rb[j] = ldx4(x, b, hh, wpix0 - P + j);
    } else {
#pragma unroll
        for (int j = 0; j < VEC + K - 1; ++j) {
            int ww = wpix0 - P + j;
            rb[j] = (ww >= 0 && ww < WW) ? ldx4(x, b, hh, ww)
                                         : float4{0.f, 0.f, 0.f, 0.f};
        }
    }
}

// full KxK conv, 4->4 ch, weights HWIO [K][K][4][4]; acc split ch{0,1}/{2,3}
template <int K>
__device__ __forceinline__ void conv_full_v(const float* __restrict__ x,
                                            const float* __restrict__ wgt,
                                            int b, int h, int wpix0, bool wsafe,
                                            f2 accl[VEC], f2 acch[VEC]) {
    constexpr int P = K / 2;
    float4 rb[VEC + K - 1];
#pragma unroll
    for (int ki = 0; ki < K; ++ki) {
        int hh = h + ki - P;              // h is wave-uniform -> uniform branch
        if ((unsigned)hh >= (unsigned)HH) continue;
        load_row<K>(x, b, hh, wpix0, wsafe, rb);
#pragma unroll
        for (int kj = 0; kj < K; ++kj) {
            const float* wp = wgt + (ki * K + kj) * 16;  // [in][out] 4x4
            f2 wl0 = {wp[0],  wp[1]},  wh0 = {wp[2],  wp[3]};
            f2 wl1 = {wp[4],  wp[5]},  wh1 = {wp[6],  wp[7]};
            f2 wl2 = {wp[8],  wp[9]},  wh2 = {wp[10], wp[11]};
            f2 wl3 = {wp[12], wp[13]}, wh3 = {wp[14], wp[15]};
#pragma unroll
            for (int v = 0; v < VEC; ++v) {
                float4 p = rb[v + kj];
                accl[v] += p.x * wl0 + p.y * wl1 + p.z * wl2 + p.w * wl3;
                acch[v] += p.x * wh0 + p.y * wh1 + p.z * wh2 + p.w * wh3;
            }
        }
    }
}

// depthwise KxK conv, weights HWIO [K][K][1][4]
template <int K>
__device__ __forceinline__ void conv_dw_v(const float* __restrict__ x,
                                          const float* __restrict__ wgt,
                                          int b, int h, int wpix0, bool wsafe,
                                          f2 accl[VEC], f2 acch[VEC]) {
    constexpr int P = K / 2;
    float4 rb[VEC + K - 1];
#pragma unroll
    for (int ki = 0; ki < K; ++ki) {
        int hh = h + ki - P;
        if ((unsigned)hh >= (unsigned)HH) continue;
        load_row<K>(x, b, hh, wpix0, wsafe, rb);
#pragma unroll
        for (int kj = 0; kj < K; ++kj) {
            const float* wp = wgt + (ki * K + kj) * 4;
            f2 wl = {wp[0], wp[1]};
            f2 wh = {wp[2], wp[3]};
#pragma unroll
            for (int v = 0; v < VEC; ++v) {
                float4 p = rb[v + kj];
                accl[v] += f2{p.x, p.y} * wl;
                acch[v] += f2{p.z, p.w} * wh;
            }
        }
    }
}

__global__ __launch_bounds__(256) void mixop_kernel(
    const float* __restrict__ x,
    const float* __restrict__ logits, const float* __restrict__ g,
    const float* __restrict__ w0, const float* __restrict__ w1,
    const float* __restrict__ w2, const float* __restrict__ w3,
    const float* __restrict__ w4,
    const float* __restrict__ gamma, const float* __restrict__ beta,
    const float* __restrict__ mean, const float* __restrict__ var,
    float* __restrict__ out) {
    int tid = blockIdx.x * blockDim.x + threadIdx.x;
    if (tid >= NTHREAD) return;

    // wave-uniform routing: argmax(logits + g), first-max wins
    int idx = 0;
    float best = logits[0] + g[0];
#pragma unroll
    for (int i = 1; i < 5; ++i) {
        float v = logits[i] + g[i];
        if (v > best) { best = v; idx = i; }
    }

    int gw = tid & (GW_N - 1);          // 7 bits
    int h  = (tid >> 7) & (HH - 1);     // 9 bits (wave-uniform)
    int b  = tid >> 16;
    int wpix0 = gw * VEC;
    bool wsafe = (gw > 0) && (gw < GW_N - 1);  // covers P<=2

    f2 accl[VEC] = {f2{0.f,0.f}, f2{0.f,0.f}, f2{0.f,0.f}, f2{0.f,0.f}};
    f2 acch[VEC] = {f2{0.f,0.f}, f2{0.f,0.f}, f2{0.f,0.f}, f2{0.f,0.f}};

    switch (idx) {
        case 0: {
            f2 wl0 = {w0[0],  w0[1]},  wh0 = {w0[2],  w0[3]};
            f2 wl1 = {w0[4],  w0[5]},  wh1 = {w0[6],  w0[7]};
            f2 wl2 = {w0[8],  w0[9]},  wh2 = {w0[10], w0[11]};
            f2 wl3 = {w0[12], w0[13]}, wh3 = {w0[14], w0[15]};
#pragma unroll
            for (int v = 0; v < VEC; ++v) {
                float4 p = ldx4(x, b, h, wpix0 + v);
                accl[v] = p.x * wl0 + p.y * wl1 + p.z * wl2 + p.w * wl3;
                acch[v] = p.x * wh0 + p.y * wh1 + p.z * wh2 + p.w * wh3;
            }
            break;
        }
        case 1: conv_full_v<3>(x, w1, b, h, wpix0, wsafe, accl, acch); break;
        case 2: conv_dw_v<3>(x, w2, b, h, wpix0, wsafe, accl, acch); break;
        case 3: conv_full_v<5>(x, w3, b, h, wpix0, wsafe, accl, acch); break;
        case 4: conv_dw_v<5>(x, w4, b, h, wpix0, wsafe, accl, acch); break;
    }

    // inference BN + ReLU; final routing scale == 1.0 exactly
    const float* ga = gamma + idx * 4;
    const float* be = beta + idx * 4;
    const float* mu = mean + idx * 4;
    const float* vr = var + idx * 4;
    f2 ivl = {ga[0] * rsqrtf(vr[0] + EPS), ga[1] * rsqrtf(vr[1] + EPS)};
    f2 ivh = {ga[2] * rsqrtf(vr[2] + EPS), ga[3] * rsqrtf(vr[3] + EPS)};
    f2 shl = f2{be[0], be[1]} - f2{mu[0], mu[1]} * ivl;
    f2 shh = f2{be[2], be[3]} - f2{mu[2], mu[3]} * ivh;

    float4* op = reinterpret_cast<float4*>(out) + (size_t)tid * VEC;
#pragma unroll
    for (int v = 0; v < VEC; ++v) {
        f2 ol = accl[v] * ivl + shl;
        f2 oh = acch[v] * ivh + shh;
        float4 o;
        o.x = ol.x > 0.f ? ol.x : 0.f;
        o.y = ol.y > 0.f ? ol.y : 0.f;
        o.z = oh.x > 0.f ? oh.x : 0.f;
        o.w = oh.y > 0.f ? oh.y : 0.f;
        op[v] = o;
    }
}

extern "C" void kernel_launch(void* const* d_in, const int* in_sizes, int n_in,
                              void* d_out, int out_size, void* d_ws, size_t ws_size,
                              hipStream_t stream) {
    const float* x      = (const float*)d_in[0];
    const float* logits = (const float*)d_in[1];
    const float* g      = (const float*)d_in[2];
    const float* w0     = (const float*)d_in[3];
    const float* w1     = (const float*)d_in[4];
    const float* w2     = (const float*)d_in[5];
    const float* w3     = (const float*)d_in[6];
    const float* w4     = (const float*)d_in[7];
    const float* gamma  = (const float*)d_in[8];
    const float* beta   = (const float*)d_in[9];
    const float* mean   = (const float*)d_in[10];
    const float* var    = (const float*)d_in[11];
    float* out = (float*)d_out;

    const int threads = 256;
    const int blocks = (NTHREAD + threads - 1) / threads;
    mixop_kernel<<<blocks, threads, 0, stream>>>(
        x, logits, g, w0, w1, w2, w3, w4, gamma, beta, mean, var, out);
}